// Round 8
// baseline (98.662 us; speedup 1.0000x reference)
//
#include <hip/hip_runtime.h>
#include <hip/hip_bf16.h>
#include <math.h>

typedef __bf16 v8bf __attribute__((ext_vector_type(8)));
typedef float  v4f  __attribute__((ext_vector_type(4)));

#define GPTR(p) ((const __attribute__((address_space(1))) void*)(p))
#define LPTR(p) ((__attribute__((address_space(3))) void*)(p))

// ---------------- prep: casts (z=0) + 6 weight transposes (z=1..6) ----------
struct PrepArgs {
    const float* x; const float* y;
    __hip_bfloat16* xb; __hip_bfloat16* yb;
    int nx4, ntot4;
    const float* wsrc[6];
    __hip_bfloat16* wdst[6];
    int K[6], N[6];
};

__global__ __launch_bounds__(256)
void prep_k(PrepArgs a) {
    const int tid = threadIdx.x, bx = blockIdx.x, z = blockIdx.z;
    if (z == 0) {
        int i = bx * 256 + tid;
        if (i >= a.ntot4) return;
        const float* src; __hip_bfloat16* dst; int j;
        if (i < a.nx4) { src = a.x; dst = a.xb; j = i; }
        else           { src = a.y; dst = a.yb; j = i - a.nx4; }
        float4 v = ((const float4*)src)[j];
        __hip_bfloat16 h[4] = {__float2bfloat16(v.x), __float2bfloat16(v.y),
                               __float2bfloat16(v.z), __float2bfloat16(v.w)};
        ((short4*)dst)[j] = *(short4*)h;
        return;
    }
    int w = z - 1;
    int K = a.K[w], N = a.N[w];
    int tn = N >> 5;
    int tt = (K >> 5) * tn;
    if (bx >= tt) return;
    int kt = (bx / tn) * 32, nt = (bx % tn) * 32;
    __shared__ float t[32][33];
    int tx = tid & 31, ty = tid >> 5; // (32,8)
    const float* W = a.wsrc[w];
    __hip_bfloat16* Wt = a.wdst[w];
#pragma unroll
    for (int i = 0; i < 4; ++i)
        t[ty + i * 8][tx] = W[(size_t)(kt + ty + i * 8) * N + nt + tx];
    __syncthreads();
#pragma unroll
    for (int i = 0; i < 4; ++i)
        Wt[(size_t)(nt + ty + i * 8) * K + kt + tx] =
            __float2bfloat16(t[tx][ty + i * 8]);
}

// ---------------- GEMM building blocks (128x128 tile, BK=64, 4 waves) -------
__device__ __forceinline__ void stage128(
    const __hip_bfloat16* __restrict__ A, const __hip_bfloat16* __restrict__ Bt,
    int lda, int ldb, int bm, int bn, int k0, int wid, int crow, int ccol,
    __hip_bfloat16* As, __hip_bfloat16* Bs) {
#pragma unroll
    for (int i = 0; i < 4; ++i) {
        int c = wid * 4 + i;
        __builtin_amdgcn_global_load_lds(
            GPTR(A + (size_t)(bm + c * 8 + crow) * lda + k0 + ccol),
            LPTR(As + c * 512), 16, 0, 0);
        __builtin_amdgcn_global_load_lds(
            GPTR(Bt + (size_t)(bn + c * 8 + crow) * ldb + k0 + ccol),
            LPTR(Bs + c * 512), 16, 0, 0);
    }
}

__device__ __forceinline__ void compute128(
    const __hip_bfloat16* As, const __hip_bfloat16* Bs,
    int lane, int wr, int wc, v4f acc[4][4]) {
#pragma unroll
    for (int kk = 0; kk < 64; kk += 32) {
        v8bf a[4], b[4];
#pragma unroll
        for (int i = 0; i < 4; ++i) {
            a[i] = *(const v8bf*)&As[(wr * 64 + i * 16 + (lane & 15)) * 64 + kk + (lane >> 4) * 8];
            b[i] = *(const v8bf*)&Bs[(wc * 64 + i * 16 + (lane & 15)) * 64 + kk + (lane >> 4) * 8];
        }
#pragma unroll
        for (int i = 0; i < 4; ++i)
#pragma unroll
            for (int j = 0; j < 4; ++j)
                acc[i][j] = __builtin_amdgcn_mfma_f32_16x16x32_bf16(
                    a[i], b[j], acc[i][j], 0, 0, 0);
    }
}

// ---------------- L1/L2 MLP GEMMs: single-buffer loop + staged epilogue -----
// Dedicated typed LDS arrays (no overlays/casts). Cs holds one 64-row
// half-tile at a time; stores are full 16B dwordx4, lane-consecutive.
struct MlpArgs {
    const __hip_bfloat16* A[2];
    const __hip_bfloat16* B[2];
    const float* bias[2];
    __hip_bfloat16* C[2];
    int K[2];
};

__global__ __launch_bounds__(256)
void gemm_mlp_k(MlpArgs args) {
    __shared__ __align__(16) __hip_bfloat16 As[128 * 64];
    __shared__ __align__(16) __hip_bfloat16 Bs[128 * 64];
    __shared__ __align__(16) __hip_bfloat16 Cs[64][136];

    const int bid = blockIdx.x;
    const int wg  = (bid & 7) * 64 + (bid >> 3);   // chunked XCD swizzle (512/8=64)
    const int z   = wg >> 8;
    const int rem = wg & 255;
    const int bm  = (rem >> 3) * 128;
    const int bn  = (rem & 7) * 128;

    const int tid = threadIdx.x, wid = tid >> 6, lane = tid & 63;
    const int wr = wid >> 1, wc = wid & 1;
    const int crow = lane >> 3, ccol = (lane & 7) * 8;
    const __hip_bfloat16* A  = args.A[z];
    const __hip_bfloat16* Bt = args.B[z];
    const int K = args.K[z];

    v4f acc[4][4] = {};
    for (int k0 = 0; k0 < K; k0 += 64) {
        stage128(A, Bt, K, K, bm, bn, k0, wid, crow, ccol, As, Bs);
        __syncthreads();
        compute128(As, Bs, lane, wr, wc, acc);
        __syncthreads();
    }

    const float* bias = args.bias[z];
    __hip_bfloat16* C = args.C[z];
#pragma unroll
    for (int p = 0; p < 2; ++p) {
        if (wr == p) {
#pragma unroll
            for (int i = 0; i < 4; ++i)
#pragma unroll
                for (int j = 0; j < 4; ++j) {
                    float bv = bias[bn + wc * 64 + j * 16 + (lane & 15)];
#pragma unroll
                    for (int r = 0; r < 4; ++r) {
                        float v = fmaxf(acc[i][j][r] + bv, 0.f);
                        Cs[i * 16 + (lane >> 4) * 4 + r]
                          [wc * 64 + j * 16 + (lane & 15)] = __float2bfloat16(v);
                    }
                }
        }
        __syncthreads();
        int row = tid >> 2, q = tid & 3;
        size_t gb = (size_t)(bm + p * 64 + row) * 1024 + bn + q * 32;
#pragma unroll
        for (int k = 0; k < 4; ++k) {
            v8bf t = *(const v8bf*)&Cs[row][q * 32 + k * 8];
            *(v8bf*)&C[gb + k * 8] = t;
        }
        __syncthreads();
    }
}

// ---------------- L3 GEMM fused with bias + L2-normalize --------------------
// Tile 32x128 (BN=128 = full LAT), K=1024 full depth, 4 waves split along N.
__global__ __launch_bounds__(256)
void gemm_l3norm_k(const __hip_bfloat16* __restrict__ As_g0,
                   const __hip_bfloat16* __restrict__ As_g1,
                   const __hip_bfloat16* __restrict__ Bt0,
                   const __hip_bfloat16* __restrict__ Bt1,
                   const float* __restrict__ sb3, const float* __restrict__ kb3,
                   __hip_bfloat16* __restrict__ zxb,
                   __hip_bfloat16* __restrict__ zyb) {
    __shared__ __align__(16) __hip_bfloat16 As[32 * 64];   // 4KB
    __shared__ __align__(16) __hip_bfloat16 Bs[128 * 64];  // 16KB
    __shared__ float red[4][32];
    const int bid = blockIdx.x;
    const int wg  = (bid & 7) * 32 + (bid >> 3);  // 256/8=32 per XCD
    const int z   = wg >> 7;
    const int bm  = (wg & 127) * 32;

    const __hip_bfloat16* A  = z ? As_g1 : As_g0;
    const __hip_bfloat16* Bt = z ? Bt1 : Bt0;
    const float* bias = z ? kb3 : sb3;
    __hip_bfloat16* zout = z ? zyb : zxb;

    const int tid = threadIdx.x, wid = tid >> 6, lane = tid & 63;
    const int crow = lane >> 3, ccol = (lane & 7) * 8;

    v4f acc[2][2] = {};
    for (int k0 = 0; k0 < 1024; k0 += 64) {
        __builtin_amdgcn_global_load_lds(
            GPTR(A + (size_t)(bm + wid * 8 + crow) * 1024 + k0 + ccol),
            LPTR(&As[wid * 512]), 16, 0, 0);
#pragma unroll
        for (int i = 0; i < 4; ++i) {
            int c = wid * 4 + i;
            __builtin_amdgcn_global_load_lds(
                GPTR(Bt + (size_t)(c * 8 + crow) * 1024 + k0 + ccol),
                LPTR(&Bs[c * 512]), 16, 0, 0);
        }
        __syncthreads();
#pragma unroll
        for (int kk = 0; kk < 64; kk += 32) {
            v8bf a[2], b[2];
#pragma unroll
            for (int i = 0; i < 2; ++i)
                a[i] = *(const v8bf*)&As[(i * 16 + (lane & 15)) * 64 + kk + (lane >> 4) * 8];
#pragma unroll
            for (int j = 0; j < 2; ++j)
                b[j] = *(const v8bf*)&Bs[(wid * 32 + j * 16 + (lane & 15)) * 64 + kk + (lane >> 4) * 8];
#pragma unroll
            for (int i = 0; i < 2; ++i)
#pragma unroll
                for (int j = 0; j < 2; ++j)
                    acc[i][j] = __builtin_amdgcn_mfma_f32_16x16x32_bf16(
                        a[i], b[j], acc[i][j], 0, 0, 0);
        }
        __syncthreads();
    }

    // bias + per-row sum of squares (this wave covers cols wid*32..wid*32+31)
    float val[2][2][4];
    float ssq[2][4];
#pragma unroll
    for (int i = 0; i < 2; ++i)
#pragma unroll
        for (int r = 0; r < 4; ++r) ssq[i][r] = 0.f;
#pragma unroll
    for (int i = 0; i < 2; ++i)
#pragma unroll
        for (int j = 0; j < 2; ++j) {
            int col = wid * 32 + j * 16 + (lane & 15);
            float bv = bias[col];
#pragma unroll
            for (int r = 0; r < 4; ++r) {
                float v = acc[i][j][r] + bv;
                val[i][j][r] = v;
                ssq[i][r] += v * v;
            }
        }
#pragma unroll
    for (int i = 0; i < 2; ++i)
#pragma unroll
        for (int r = 0; r < 4; ++r) {
#pragma unroll
            for (int m = 1; m < 16; m <<= 1)
                ssq[i][r] += __shfl_xor(ssq[i][r], m, 64);
            if ((lane & 15) == 0)
                red[wid][i * 16 + (lane >> 4) * 4 + r] = ssq[i][r];
        }
    __syncthreads();
#pragma unroll
    for (int i = 0; i < 2; ++i)
#pragma unroll
        for (int r = 0; r < 4; ++r) {
            int row = i * 16 + (lane >> 4) * 4 + r;
            float ss = red[0][row] + red[1][row] + red[2][row] + red[3][row];
            float inv = 1.0f / fmaxf(sqrtf(ss), 1e-12f);
#pragma unroll
            for (int j = 0; j < 2; ++j) {
                int col = wid * 32 + j * 16 + (lane & 15);
                zout[(size_t)(bm + row) * 128 + col] =
                    __float2bfloat16(val[i][j][r] * inv);
            }
        }
}

// ---------------- scores GEMM + fused per-row partial exp-sums --------------
// R4-verbatim (passing): scattered scalar nontemporal stores + rowsum.
// scores in [-1,1] (cosine/TEMP), so lse = 1 + log(sum exp(s-1)) needs no max.
__global__ __launch_bounds__(256)
void gemm_scores_k(const __hip_bfloat16* __restrict__ zxb,
                   const __hip_bfloat16* __restrict__ zyb,
                   float* __restrict__ out, float* __restrict__ esum) {
    __shared__ __align__(16) __hip_bfloat16 As[128 * 64], Bs[128 * 64];
    __shared__ float rowsum[2][128];
    const int tid = threadIdx.x, wid = tid >> 6, lane = tid & 63;
    const int wr = wid >> 1, wc = wid & 1;
    const int bm = blockIdx.x * 128, bn = blockIdx.y * 128;
    const int crow = lane >> 3, ccol = (lane & 7) * 8;
    v4f acc[4][4] = {};
#pragma unroll
    for (int t = 0; t < 2; ++t) {
        stage128(zxb, zyb, 128, 128, bm, bn, t * 64, wid, crow, ccol, As, Bs);
        __syncthreads();
        compute128(As, Bs, lane, wr, wc, acc);
        __syncthreads();
    }
#pragma unroll
    for (int i = 0; i < 4; ++i) {
        int rowb = bm + wr * 64 + i * 16 + (lane >> 4) * 4;
#pragma unroll
        for (int r = 0; r < 4; ++r) {
            float s = 0.f;
#pragma unroll
            for (int j = 0; j < 4; ++j) {
                int col = bn + wc * 64 + j * 16 + (lane & 15);
                float v = acc[i][j][r];
                __builtin_nontemporal_store(v, &out[(size_t)(rowb + r) * 4096 + col]);
                s += __expf(v - 1.0f);
            }
#pragma unroll
            for (int m = 1; m < 16; m <<= 1) s += __shfl_xor(s, m, 64);
            if ((lane & 15) == 0)
                rowsum[wc][wr * 64 + i * 16 + (lane >> 4) * 4 + r] = s;
        }
    }
    __syncthreads();
    if (tid < 128)
        esum[(size_t)(bm + tid) * 32 + blockIdx.y] =
            rowsum[0][tid] + rowsum[1][tid];
}

// ---------------- mi from partial exp-sums + diag ---------------------------
__global__ __launch_bounds__(256)
void mi_k(const float* __restrict__ esum, const float* __restrict__ scores,
          float* __restrict__ mi) {
    int row = blockIdx.x * 256 + threadIdx.x;
    const float4* p = (const float4*)&esum[(size_t)row * 32];
    float s = 0.f;
#pragma unroll
    for (int i = 0; i < 8; ++i) { float4 v = p[i]; s += v.x + v.y + v.z + v.w; }
    float diag = scores[(size_t)row * 4096 + row];
    // mi = log(4096) + diag - (1 + log(sum))
    mi[row] = 8.317766166719343f + diag - 1.0f - logf(s);
}

// ---------------------------------------------------------------------------
extern "C" void kernel_launch(void* const* d_in, const int* in_sizes, int n_in,
                              void* d_out, int out_size, void* d_ws, size_t ws_size,
                              hipStream_t stream) {
    const float* x   = (const float*)d_in[0];
    const float* y   = (const float*)d_in[1];
    const float* sW1 = (const float*)d_in[2];
    const float* sb1 = (const float*)d_in[3];
    const float* sW2 = (const float*)d_in[4];
    const float* sb2 = (const float*)d_in[5];
    const float* sW3 = (const float*)d_in[6];
    const float* sb3 = (const float*)d_in[7];
    const float* kW1 = (const float*)d_in[8];
    const float* kb1 = (const float*)d_in[9];
    const float* kW2 = (const float*)d_in[10];
    const float* kb2 = (const float*)d_in[11];
    const float* kW3 = (const float*)d_in[12];
    const float* kb3 = (const float*)d_in[13];

    float* out = (float*)d_out;              // scores [4096][4096]
    float* mi  = out + (size_t)4096 * 4096;  // mi [4096]

    char* ws = (char*)d_ws;
    auto alloc = [&](size_t bytes) {
        char* p = ws;
        ws += (bytes + 255) & ~(size_t)255;
        return p;
    };
    __hip_bfloat16* xb   = (__hip_bfloat16*)alloc((size_t)4096 * 256 * 2);
    __hip_bfloat16* yb   = (__hip_bfloat16*)alloc((size_t)4096 * 64 * 2);
    __hip_bfloat16* sW1t = (__hip_bfloat16*)alloc((size_t)1024 * 256 * 2);
    __hip_bfloat16* sW2t = (__hip_bfloat16*)alloc((size_t)1024 * 1024 * 2);
    __hip_bfloat16* sW3t = (__hip_bfloat16*)alloc((size_t)128 * 1024 * 2);
    __hip_bfloat16* kW1t = (__hip_bfloat16*)alloc((size_t)1024 * 64 * 2);
    __hip_bfloat16* kW2t = (__hip_bfloat16*)alloc((size_t)1024 * 1024 * 2);
    __hip_bfloat16* kW3t = (__hip_bfloat16*)alloc((size_t)128 * 1024 * 2);
    __hip_bfloat16* h1s  = (__hip_bfloat16*)alloc((size_t)4096 * 1024 * 2);
    __hip_bfloat16* h1k  = (__hip_bfloat16*)alloc((size_t)4096 * 1024 * 2);
    __hip_bfloat16* h2s  = (__hip_bfloat16*)alloc((size_t)4096 * 1024 * 2);
    __hip_bfloat16* h2k  = (__hip_bfloat16*)alloc((size_t)4096 * 1024 * 2);
    float*          es   = (float*)alloc((size_t)4096 * 32 * 4);
    __hip_bfloat16* zxb  = (__hip_bfloat16*)alloc((size_t)4096 * 128 * 2);
    __hip_bfloat16* zyb  = (__hip_bfloat16*)alloc((size_t)4096 * 128 * 2);

    // K1: prep (casts + all weight transposes)
    PrepArgs pa;
    pa.x = x; pa.y = y; pa.xb = xb; pa.yb = yb;
    pa.nx4 = 4096 * 256 / 4;
    pa.ntot4 = pa.nx4 + 4096 * 64 / 4;
    pa.wsrc[0] = sW1; pa.wdst[0] = sW1t; pa.K[0] = 256;  pa.N[0] = 1024;
    pa.wsrc[1] = sW2; pa.wdst[1] = sW2t; pa.K[1] = 1024; pa.N[1] = 1024;
    pa.wsrc[2] = sW3; pa.wdst[2] = sW3t; pa.K[2] = 1024; pa.N[2] = 128;
    pa.wsrc[3] = kW1; pa.wdst[3] = kW1t; pa.K[3] = 64;   pa.N[3] = 1024;
    pa.wsrc[4] = kW2; pa.wdst[4] = kW2t; pa.K[4] = 1024; pa.N[4] = 1024;
    pa.wsrc[5] = kW3; pa.wdst[5] = kW3t; pa.K[5] = 1024; pa.N[5] = 128;
    prep_k<<<dim3(1280, 1, 7), 256, 0, stream>>>(pa);

    // K2: L1 GEMMs (both MLPs)
    MlpArgs l1;
    l1.A[0] = xb;  l1.B[0] = sW1t; l1.bias[0] = sb1; l1.C[0] = h1s; l1.K[0] = 256;
    l1.A[1] = yb;  l1.B[1] = kW1t; l1.bias[1] = kb1; l1.C[1] = h1k; l1.K[1] = 64;
    gemm_mlp_k<<<512, 256, 0, stream>>>(l1);

    // K3: L2 GEMMs (both MLPs)
    MlpArgs l2;
    l2.A[0] = h1s; l2.B[0] = sW2t; l2.bias[0] = sb2; l2.C[0] = h2s; l2.K[0] = 1024;
    l2.A[1] = h1k; l2.B[1] = kW2t; l2.bias[1] = kb2; l2.C[1] = h2k; l2.K[1] = 1024;
    gemm_mlp_k<<<512, 256, 0, stream>>>(l2);

    // K4: L3 GEMM + bias + normalize (both MLPs), 32-row tiles
    gemm_l3norm_k<<<256, 256, 0, stream>>>(
        h2s, h2k, sW3t, kW3t, sb3, kb3, zxb, zyb);

    // K5: scores GEMM + fused partial exp-sums
    gemm_scores_k<<<dim3(32, 32), 256, 0, stream>>>(zxb, zyb, out, es);

    // K6: mi
    mi_k<<<16, 256, 0, stream>>>(es, out, mi);
}

// Round 9
// 90.033 us; speedup vs baseline: 1.0958x; 1.0958x over previous
//
#include <hip/hip_runtime.h>
#include <hip/hip_bf16.h>
#include <math.h>

typedef __bf16 v8bf __attribute__((ext_vector_type(8)));
typedef float  v4f  __attribute__((ext_vector_type(4)));

#define GPTR(p) ((const __attribute__((address_space(1))) void*)(p))
#define LPTR(p) ((__attribute__((address_space(3))) void*)(p))

// ---------------- prep: casts (z=0) + 6 weight transposes (z=1..6) ----------
struct PrepArgs {
    const float* x; const float* y;
    __hip_bfloat16* xb; __hip_bfloat16* yb;
    int nx4, ntot4;
    const float* wsrc[6];
    __hip_bfloat16* wdst[6];
    int K[6], N[6];
};

__global__ __launch_bounds__(256)
void prep_k(PrepArgs a) {
    const int tid = threadIdx.x, bx = blockIdx.x, z = blockIdx.z;
    if (z == 0) {
        int i = bx * 256 + tid;
        if (i >= a.ntot4) return;
        const float* src; __hip_bfloat16* dst; int j;
        if (i < a.nx4) { src = a.x; dst = a.xb; j = i; }
        else           { src = a.y; dst = a.yb; j = i - a.nx4; }
        float4 v = ((const float4*)src)[j];
        __hip_bfloat16 h[4] = {__float2bfloat16(v.x), __float2bfloat16(v.y),
                               __float2bfloat16(v.z), __float2bfloat16(v.w)};
        ((short4*)dst)[j] = *(short4*)h;
        return;
    }
    int w = z - 1;
    int K = a.K[w], N = a.N[w];
    int tn = N >> 5;
    int tt = (K >> 5) * tn;
    if (bx >= tt) return;
    int kt = (bx / tn) * 32, nt = (bx % tn) * 32;
    __shared__ float t[32][33];
    int tx = tid & 31, ty = tid >> 5; // (32,8)
    const float* W = a.wsrc[w];
    __hip_bfloat16* Wt = a.wdst[w];
#pragma unroll
    for (int i = 0; i < 4; ++i)
        t[ty + i * 8][tx] = W[(size_t)(kt + ty + i * 8) * N + nt + tx];
    __syncthreads();
#pragma unroll
    for (int i = 0; i < 4; ++i)
        Wt[(size_t)(nt + ty + i * 8) * K + kt + tx] =
            __float2bfloat16(t[tx][ty + i * 8]);
}

// ---------------- GEMM building blocks (128x128 tile, BK=64, 4 waves) -------
__device__ __forceinline__ void stage128(
    const __hip_bfloat16* __restrict__ A, const __hip_bfloat16* __restrict__ Bt,
    int lda, int ldb, int bm, int bn, int k0, int wid, int crow, int ccol,
    __hip_bfloat16* As, __hip_bfloat16* Bs) {
#pragma unroll
    for (int i = 0; i < 4; ++i) {
        int c = wid * 4 + i;
        __builtin_amdgcn_global_load_lds(
            GPTR(A + (size_t)(bm + c * 8 + crow) * lda + k0 + ccol),
            LPTR(As + c * 512), 16, 0, 0);
        __builtin_amdgcn_global_load_lds(
            GPTR(Bt + (size_t)(bn + c * 8 + crow) * ldb + k0 + ccol),
            LPTR(Bs + c * 512), 16, 0, 0);
    }
}

__device__ __forceinline__ void compute128(
    const __hip_bfloat16* As, const __hip_bfloat16* Bs,
    int lane, int wr, int wc, v4f acc[4][4]) {
#pragma unroll
    for (int kk = 0; kk < 64; kk += 32) {
        v8bf a[4], b[4];
#pragma unroll
        for (int i = 0; i < 4; ++i) {
            a[i] = *(const v8bf*)&As[(wr * 64 + i * 16 + (lane & 15)) * 64 + kk + (lane >> 4) * 8];
            b[i] = *(const v8bf*)&Bs[(wc * 64 + i * 16 + (lane & 15)) * 64 + kk + (lane >> 4) * 8];
        }
#pragma unroll
        for (int i = 0; i < 4; ++i)
#pragma unroll
            for (int j = 0; j < 4; ++j)
                acc[i][j] = __builtin_amdgcn_mfma_f32_16x16x32_bf16(
                    a[i], b[j], acc[i][j], 0, 0, 0);
    }
}

// ---------------- L1/L2 MLP GEMMs: prefetch-dbuf (T3-min), direct stores ----
// Per K-step: issue stage(t+1) into buf^1, compute(t) from buf, ONE
// __syncthreads (its built-in vmcnt/lgkm drain lands AFTER compute has
// covered the load latency). Dedicated typed LDS arrays only.
struct MlpArgs {
    const __hip_bfloat16* A[2];
    const __hip_bfloat16* B[2];
    const float* bias[2];
    __hip_bfloat16* C[2];
    int K[2];
};

__global__ __launch_bounds__(256)
void gemm_mlp_k(MlpArgs args) {
    __shared__ __align__(16) __hip_bfloat16 As0[128 * 64], As1[128 * 64];
    __shared__ __align__(16) __hip_bfloat16 Bs0[128 * 64], Bs1[128 * 64];

    const int bid = blockIdx.x;
    const int wg  = (bid & 7) * 64 + (bid >> 3);   // chunked XCD swizzle (512/8=64)
    const int z   = wg >> 8;
    const int rem = wg & 255;
    const int bm  = (rem >> 3) * 128;
    const int bn  = (rem & 7) * 128;

    const int tid = threadIdx.x, wid = tid >> 6, lane = tid & 63;
    const int wr = wid >> 1, wc = wid & 1;
    const int crow = lane >> 3, ccol = (lane & 7) * 8;
    const __hip_bfloat16* A  = args.A[z];
    const __hip_bfloat16* Bt = args.B[z];
    const int K = args.K[z];
    const int nt = K >> 6;

    v4f acc[4][4] = {};
    stage128(A, Bt, K, K, bm, bn, 0, wid, crow, ccol, As0, Bs0);
    __syncthreads();
    for (int t = 0; t < nt; ++t) {
        const bool odd = t & 1;
        if (t + 1 < nt)
            stage128(A, Bt, K, K, bm, bn, (t + 1) * 64, wid, crow, ccol,
                     odd ? As0 : As1, odd ? Bs0 : Bs1);
        compute128(odd ? As1 : As0, odd ? Bs1 : Bs0, lane, wr, wc, acc);
        __syncthreads();
    }

    const float* bias = args.bias[z];
    __hip_bfloat16* C = args.C[z];
#pragma unroll
    for (int i = 0; i < 4; ++i) {
        int rowb = bm + wr * 64 + i * 16 + (lane >> 4) * 4;
#pragma unroll
        for (int j = 0; j < 4; ++j) {
            int col = bn + wc * 64 + j * 16 + (lane & 15);
            float bv = bias[col];
#pragma unroll
            for (int r = 0; r < 4; ++r) {
                float v = fmaxf(acc[i][j][r] + bv, 0.f);
                C[(size_t)(rowb + r) * 1024 + col] = __float2bfloat16(v);
            }
        }
    }
}

// ---------------- L3 GEMM fused with bias + L2-normalize (prefetch-dbuf) ----
// Tile 32x128 (BN=128 = full LAT), K=1024 full depth, 4 waves split along N.
__global__ __launch_bounds__(256)
void gemm_l3norm_k(const __hip_bfloat16* __restrict__ As_g0,
                   const __hip_bfloat16* __restrict__ As_g1,
                   const __hip_bfloat16* __restrict__ Bt0,
                   const __hip_bfloat16* __restrict__ Bt1,
                   const float* __restrict__ sb3, const float* __restrict__ kb3,
                   __hip_bfloat16* __restrict__ zxb,
                   __hip_bfloat16* __restrict__ zyb) {
    __shared__ __align__(16) __hip_bfloat16 As[2][32 * 64];   // 2x4KB
    __shared__ __align__(16) __hip_bfloat16 Bs[2][128 * 64];  // 2x16KB
    __shared__ float red[4][32];
    const int bid = blockIdx.x;
    const int wg  = (bid & 7) * 32 + (bid >> 3);  // 256/8=32 per XCD
    const int z   = wg >> 7;
    const int bm  = (wg & 127) * 32;

    const __hip_bfloat16* A  = z ? As_g1 : As_g0;
    const __hip_bfloat16* Bt = z ? Bt1 : Bt0;
    const float* bias = z ? kb3 : sb3;
    __hip_bfloat16* zout = z ? zyb : zxb;

    const int tid = threadIdx.x, wid = tid >> 6, lane = tid & 63;
    const int crow = lane >> 3, ccol = (lane & 7) * 8;

    auto stage = [&](int buf, int k0) {
        __builtin_amdgcn_global_load_lds(
            GPTR(A + (size_t)(bm + wid * 8 + crow) * 1024 + k0 + ccol),
            LPTR(&As[buf][wid * 512]), 16, 0, 0);
#pragma unroll
        for (int i = 0; i < 4; ++i) {
            int c = wid * 4 + i;
            __builtin_amdgcn_global_load_lds(
                GPTR(Bt + (size_t)(c * 8 + crow) * 1024 + k0 + ccol),
                LPTR(&Bs[buf][c * 512]), 16, 0, 0);
        }
    };
    auto compute = [&](int buf, v4f acc[2][2]) {
#pragma unroll
        for (int kk = 0; kk < 64; kk += 32) {
            v8bf a[2], b[2];
#pragma unroll
            for (int i = 0; i < 2; ++i)
                a[i] = *(const v8bf*)&As[buf][(i * 16 + (lane & 15)) * 64 + kk + (lane >> 4) * 8];
#pragma unroll
            for (int j = 0; j < 2; ++j)
                b[j] = *(const v8bf*)&Bs[buf][(wid * 32 + j * 16 + (lane & 15)) * 64 + kk + (lane >> 4) * 8];
#pragma unroll
            for (int i = 0; i < 2; ++i)
#pragma unroll
                for (int j = 0; j < 2; ++j)
                    acc[i][j] = __builtin_amdgcn_mfma_f32_16x16x32_bf16(
                        a[i], b[j], acc[i][j], 0, 0, 0);
        }
    };

    v4f acc[2][2] = {};
    stage(0, 0);
    __syncthreads();
    for (int t = 0; t < 16; ++t) {
        const int cur = t & 1;
        if (t + 1 < 16) stage(cur ^ 1, (t + 1) * 64);
        compute(cur, acc);
        __syncthreads();
    }

    // bias + per-row sum of squares (this wave covers cols wid*32..wid*32+31)
    float val[2][2][4];
    float ssq[2][4];
#pragma unroll
    for (int i = 0; i < 2; ++i)
#pragma unroll
        for (int r = 0; r < 4; ++r) ssq[i][r] = 0.f;
#pragma unroll
    for (int i = 0; i < 2; ++i)
#pragma unroll
        for (int j = 0; j < 2; ++j) {
            int col = wid * 32 + j * 16 + (lane & 15);
            float bv = bias[col];
#pragma unroll
            for (int r = 0; r < 4; ++r) {
                float v = acc[i][j][r] + bv;
                val[i][j][r] = v;
                ssq[i][r] += v * v;
            }
        }
#pragma unroll
    for (int i = 0; i < 2; ++i)
#pragma unroll
        for (int r = 0; r < 4; ++r) {
#pragma unroll
            for (int m = 1; m < 16; m <<= 1)
                ssq[i][r] += __shfl_xor(ssq[i][r], m, 64);
            if ((lane & 15) == 0)
                red[wid][i * 16 + (lane >> 4) * 4 + r] = ssq[i][r];
        }
    __syncthreads();
#pragma unroll
    for (int i = 0; i < 2; ++i)
#pragma unroll
        for (int r = 0; r < 4; ++r) {
            int row = i * 16 + (lane >> 4) * 4 + r;
            float ss = red[0][row] + red[1][row] + red[2][row] + red[3][row];
            float inv = 1.0f / fmaxf(sqrtf(ss), 1e-12f);
#pragma unroll
            for (int j = 0; j < 2; ++j) {
                int col = wid * 32 + j * 16 + (lane & 15);
                zout[(size_t)(bm + row) * 128 + col] =
                    __float2bfloat16(val[i][j][r] * inv);
            }
        }
}

// ---------------- scores GEMM + fused per-row partial exp-sums --------------
// R4-verbatim (passing): scattered scalar nontemporal stores + rowsum.
// scores in [-1,1] (cosine/TEMP), so lse = 1 + log(sum exp(s-1)) needs no max.
__global__ __launch_bounds__(256)
void gemm_scores_k(const __hip_bfloat16* __restrict__ zxb,
                   const __hip_bfloat16* __restrict__ zyb,
                   float* __restrict__ out, float* __restrict__ esum) {
    __shared__ __align__(16) __hip_bfloat16 As[128 * 64], Bs[128 * 64];
    __shared__ float rowsum[2][128];
    const int tid = threadIdx.x, wid = tid >> 6, lane = tid & 63;
    const int wr = wid >> 1, wc = wid & 1;
    const int bm = blockIdx.x * 128, bn = blockIdx.y * 128;
    const int crow = lane >> 3, ccol = (lane & 7) * 8;
    v4f acc[4][4] = {};
#pragma unroll
    for (int t = 0; t < 2; ++t) {
        stage128(zxb, zyb, 128, 128, bm, bn, t * 64, wid, crow, ccol, As, Bs);
        __syncthreads();
        compute128(As, Bs, lane, wr, wc, acc);
        __syncthreads();
    }
#pragma unroll
    for (int i = 0; i < 4; ++i) {
        int rowb = bm + wr * 64 + i * 16 + (lane >> 4) * 4;
#pragma unroll
        for (int r = 0; r < 4; ++r) {
            float s = 0.f;
#pragma unroll
            for (int j = 0; j < 4; ++j) {
                int col = bn + wc * 64 + j * 16 + (lane & 15);
                float v = acc[i][j][r];
                __builtin_nontemporal_store(v, &out[(size_t)(rowb + r) * 4096 + col]);
                s += __expf(v - 1.0f);
            }
#pragma unroll
            for (int m = 1; m < 16; m <<= 1) s += __shfl_xor(s, m, 64);
            if ((lane & 15) == 0)
                rowsum[wc][wr * 64 + i * 16 + (lane >> 4) * 4 + r] = s;
        }
    }
    __syncthreads();
    if (tid < 128)
        esum[(size_t)(bm + tid) * 32 + blockIdx.y] =
            rowsum[0][tid] + rowsum[1][tid];
}

// ---------------- mi from partial exp-sums + diag ---------------------------
__global__ __launch_bounds__(256)
void mi_k(const float* __restrict__ esum, const float* __restrict__ scores,
          float* __restrict__ mi) {
    int row = blockIdx.x * 256 + threadIdx.x;
    const float4* p = (const float4*)&esum[(size_t)row * 32];
    float s = 0.f;
#pragma unroll
    for (int i = 0; i < 8; ++i) { float4 v = p[i]; s += v.x + v.y + v.z + v.w; }
    float diag = scores[(size_t)row * 4096 + row];
    // mi = log(4096) + diag - (1 + log(sum))
    mi[row] = 8.317766166719343f + diag - 1.0f - logf(s);
}

// ---------------------------------------------------------------------------
extern "C" void kernel_launch(void* const* d_in, const int* in_sizes, int n_in,
                              void* d_out, int out_size, void* d_ws, size_t ws_size,
                              hipStream_t stream) {
    const float* x   = (const float*)d_in[0];
    const float* y   = (const float*)d_in[1];
    const float* sW1 = (const float*)d_in[2];
    const float* sb1 = (const float*)d_in[3];
    const float* sW2 = (const float*)d_in[4];
    const float* sb2 = (const float*)d_in[5];
    const float* sW3 = (const float*)d_in[6];
    const float* sb3 = (const float*)d_in[7];
    const float* kW1 = (const float*)d_in[8];
    const float* kb1 = (const float*)d_in[9];
    const float* kW2 = (const float*)d_in[10];
    const float* kb2 = (const float*)d_in[11];
    const float* kW3 = (const float*)d_in[12];
    const float* kb3 = (const float*)d_in[13];

    float* out = (float*)d_out;              // scores [4096][4096]
    float* mi  = out + (size_t)4096 * 4096;  // mi [4096]

    char* ws = (char*)d_ws;
    auto alloc = [&](size_t bytes) {
        char* p = ws;
        ws += (bytes + 255) & ~(size_t)255;
        return p;
    };
    __hip_bfloat16* xb   = (__hip_bfloat16*)alloc((size_t)4096 * 256 * 2);
    __hip_bfloat16* yb   = (__hip_bfloat16*)alloc((size_t)4096 * 64 * 2);
    __hip_bfloat16* sW1t = (__hip_bfloat16*)alloc((size_t)1024 * 256 * 2);
    __hip_bfloat16* sW2t = (__hip_bfloat16*)alloc((size_t)1024 * 1024 * 2);
    __hip_bfloat16* sW3t = (__hip_bfloat16*)alloc((size_t)128 * 1024 * 2);
    __hip_bfloat16* kW1t = (__hip_bfloat16*)alloc((size_t)1024 * 64 * 2);
    __hip_bfloat16* kW2t = (__hip_bfloat16*)alloc((size_t)1024 * 1024 * 2);
    __hip_bfloat16* kW3t = (__hip_bfloat16*)alloc((size_t)128 * 1024 * 2);
    __hip_bfloat16* h1s  = (__hip_bfloat16*)alloc((size_t)4096 * 1024 * 2);
    __hip_bfloat16* h1k  = (__hip_bfloat16*)alloc((size_t)4096 * 1024 * 2);
    __hip_bfloat16* h2s  = (__hip_bfloat16*)alloc((size_t)4096 * 1024 * 2);
    __hip_bfloat16* h2k  = (__hip_bfloat16*)alloc((size_t)4096 * 1024 * 2);
    float*          es   = (float*)alloc((size_t)4096 * 32 * 4);
    __hip_bfloat16* zxb  = (__hip_bfloat16*)alloc((size_t)4096 * 128 * 2);
    __hip_bfloat16* zyb  = (__hip_bfloat16*)alloc((size_t)4096 * 128 * 2);

    // K1: prep (casts + all weight transposes)
    PrepArgs pa;
    pa.x = x; pa.y = y; pa.xb = xb; pa.yb = yb;
    pa.nx4 = 4096 * 256 / 4;
    pa.ntot4 = pa.nx4 + 4096 * 64 / 4;
    pa.wsrc[0] = sW1; pa.wdst[0] = sW1t; pa.K[0] = 256;  pa.N[0] = 1024;
    pa.wsrc[1] = sW2; pa.wdst[1] = sW2t; pa.K[1] = 1024; pa.N[1] = 1024;
    pa.wsrc[2] = sW3; pa.wdst[2] = sW3t; pa.K[2] = 1024; pa.N[2] = 128;
    pa.wsrc[3] = kW1; pa.wdst[3] = kW1t; pa.K[3] = 64;   pa.N[3] = 1024;
    pa.wsrc[4] = kW2; pa.wdst[4] = kW2t; pa.K[4] = 1024; pa.N[4] = 1024;
    pa.wsrc[5] = kW3; pa.wdst[5] = kW3t; pa.K[5] = 1024; pa.N[5] = 128;
    prep_k<<<dim3(1280, 1, 7), 256, 0, stream>>>(pa);

    // K2: L1 GEMMs (both MLPs)
    MlpArgs l1;
    l1.A[0] = xb;  l1.B[0] = sW1t; l1.bias[0] = sb1; l1.C[0] = h1s; l1.K[0] = 256;
    l1.A[1] = yb;  l1.B[1] = kW1t; l1.bias[1] = kb1; l1.C[1] = h1k; l1.K[1] = 64;
    gemm_mlp_k<<<512, 256, 0, stream>>>(l1);

    // K3: L2 GEMMs (both MLPs)
    MlpArgs l2;
    l2.A[0] = h1s; l2.B[0] = sW2t; l2.bias[0] = sb2; l2.C[0] = h2s; l2.K[0] = 1024;
    l2.A[1] = h1k; l2.B[1] = kW2t; l2.bias[1] = kb2; l2.C[1] = h2k; l2.K[1] = 1024;
    gemm_mlp_k<<<512, 256, 0, stream>>>(l2);

    // K4: L3 GEMM + bias + normalize (both MLPs), 32-row tiles
    gemm_l3norm_k<<<256, 256, 0, stream>>>(
        h2s, h2k, sW3t, kW3t, sb3, kb3, zxb, zyb);

    // K5: scores GEMM + fused partial exp-sums
    gemm_scores_k<<<dim3(32, 32), 256, 0, stream>>>(zxb, zyb, out, es);

    // K6: mi
    mi_k<<<16, 256, 0, stream>>>(es, out, mi);
}